// Round 1
// baseline (162.760 us; speedup 1.0000x reference)
//
#include <hip/hip_runtime.h>
#include <hip/hip_bf16.h>
#include <stdint.h>

typedef __bf16 bf16;
typedef __bf16 bf16x8 __attribute__((ext_vector_type(8)));
typedef float f32x4 __attribute__((ext_vector_type(4)));

#define GAS __attribute__((address_space(1)))
#define LAS __attribute__((address_space(3)))

static constexpr int M = 4096;   // batch
static constexpr int N = 2048;   // 2C
static constexpr int K = 2048;   // 2C

// --- async global->LDS, 16B per lane, dest = wave-uniform base + lane*16 ---
__device__ __forceinline__ void gload_lds16(const bf16* gsrc, bf16* ldst) {
    __builtin_amdgcn_global_load_lds((const GAS void*)gsrc, (LAS void*)ldst, 16, 0, 0);
}

// --- pack concat(x0,x1) [M][K] fp32 -> bf16, vectorized 8 elems/thread ---
__global__ __launch_bounds__(256) void pack_x_kernel(const float* __restrict__ x0,
                                                     const float* __restrict__ x1,
                                                     bf16* __restrict__ A) {
    int idx = (blockIdx.x * 256 + threadIdx.x) * 8;   // 2048 elems per row, 8-chunks never straddle the 1024 seam
    int b = idx >> 11;
    int c = idx & 2047;
    const float* src = (c < 1024) ? (x0 + (size_t)b * 1024 + c)
                                  : (x1 + (size_t)b * 1024 + (c - 1024));
    float4 v0 = *reinterpret_cast<const float4*>(src);
    float4 v1 = *reinterpret_cast<const float4*>(src + 4);
    bf16x8 o;
    o[0] = (bf16)v0.x; o[1] = (bf16)v0.y; o[2] = (bf16)v0.z; o[3] = (bf16)v0.w;
    o[4] = (bf16)v1.x; o[5] = (bf16)v1.y; o[6] = (bf16)v1.z; o[7] = (bf16)v1.w;
    *reinterpret_cast<bf16x8*>(A + idx) = o;
}

// --- W [K][N] fp32 -> Wt [N][K] bf16 (LDS-tiled transpose, coalesced both sides) ---
__global__ __launch_bounds__(256) void transpose_w_kernel(const float* __restrict__ W,
                                                          bf16* __restrict__ Wt) {
    __shared__ bf16 tile[32][33];
    int n0 = blockIdx.x * 32;
    int k0 = blockIdx.y * 32;
    int tx = threadIdx.x;   // 0..31
    int ty = threadIdx.y;   // 0..7
    #pragma unroll
    for (int i = 0; i < 4; i++) {
        int k = ty + i * 8;
        tile[k][tx] = (bf16)W[(size_t)(k0 + k) * N + n0 + tx];
    }
    __syncthreads();
    #pragma unroll
    for (int i = 0; i < 4; i++) {
        int n = ty + i * 8;
        Wt[(size_t)(n0 + n) * K + k0 + tx] = tile[tx][n];   // Wt[n][k] = W[k][n]
    }
}

// --- 128x128-tile bf16 GEMM, m97 structure: BK=32, 4 waves (2x2 of 64x64),
//     global_load_lds staging, 2-barrier K-loop, 16x mfma_16x16x32 per step ---
template <bool OUT_BF16>
__global__ __launch_bounds__(256, 2) void gemm_kernel(const bf16* __restrict__ A,   // [M][K]
                                                      const bf16* __restrict__ Bt,  // [N][K] (W^T)
                                                      void* __restrict__ Cout) {    // [M][N]
    __shared__ bf16 As[128 * 32];
    __shared__ bf16 Bs[128 * 32];

    // XCD-aware bijective swizzle (512 blocks, 512 % 8 == 0)
    int bid = blockIdx.x;
    int cpx = gridDim.x >> 3;
    int swz = (bid & 7) * cpx + (bid >> 3);
    constexpr int ntn = N / 128;          // 16
    int tm = swz / ntn;
    int tn = swz % ntn;

    int tid  = threadIdx.x;
    int wave = tid >> 6;
    int lane = tid & 63;
    int wr = wave >> 1;                   // wave's 64x64 quadrant
    int wc = wave & 1;

    f32x4 acc[4][4] = {};

    // staging: each wave stages 32 rows (2 x 16-row gload_lds16) of A and of Bt
    int rowA = wave * 32 + (lane >> 2);
    int colA = (lane & 3) * 8;
    const bf16* aSrc = A  + (size_t)(tm * 128 + rowA) * K + colA;
    const bf16* bSrc = Bt + (size_t)(tn * 128 + rowA) * K + colA;
    bf16* ldsA0 = &As[(wave * 32) * 32];
    bf16* ldsA1 = &As[(wave * 32 + 16) * 32];
    bf16* ldsB0 = &Bs[(wave * 32) * 32];
    bf16* ldsB1 = &Bs[(wave * 32 + 16) * 32];

    // fragment reads: same (lane-group,elem)->k bijection for A and B => correct by k-permutation invariance
    int fr = lane & 15;
    int fb = lane >> 4;
    const bf16* aRead = &As[(wr * 64 + fr) * 32 + fb * 8];
    const bf16* bRead = &Bs[(wc * 64 + fr) * 32 + fb * 8];

    for (int k0 = 0; k0 < K; k0 += 32) {
        __syncthreads();                              // prev compute done before overwrite
        gload_lds16(aSrc + k0,          ldsA0);
        gload_lds16(aSrc + 16 * K + k0, ldsA1);
        gload_lds16(bSrc + k0,          ldsB0);
        gload_lds16(bSrc + 16 * K + k0, ldsB1);
        __syncthreads();                              // compiler drains vmcnt(0) before barrier

        bf16x8 af[4], bfr[4];
        #pragma unroll
        for (int mi = 0; mi < 4; mi++)
            af[mi] = *reinterpret_cast<const bf16x8*>(aRead + mi * 16 * 32);
        #pragma unroll
        for (int ni = 0; ni < 4; ni++)
            bfr[ni] = *reinterpret_cast<const bf16x8*>(bRead + ni * 16 * 32);

        #pragma unroll
        for (int mi = 0; mi < 4; mi++)
            #pragma unroll
            for (int ni = 0; ni < 4; ni++)
                acc[mi][ni] = __builtin_amdgcn_mfma_f32_16x16x32_bf16(af[mi], bfr[ni], acc[mi][ni], 0, 0, 0);
    }

    // epilogue: C/D layout (measured): col = lane&15, row = (lane>>4)*4 + reg
    int row0 = tm * 128 + wr * 64 + (lane >> 4) * 4;
    int col0 = tn * 128 + wc * 64 + (lane & 15);
    if constexpr (OUT_BF16) {
        bf16* C = (bf16*)Cout;
        #pragma unroll
        for (int mi = 0; mi < 4; mi++)
            #pragma unroll
            for (int r = 0; r < 4; r++) {
                size_t base = (size_t)(row0 + mi * 16 + r) * N + col0;
                #pragma unroll
                for (int ni = 0; ni < 4; ni++)
                    C[base + ni * 16] = (bf16)acc[mi][ni][r];
            }
    } else {
        float* C = (float*)Cout;
        #pragma unroll
        for (int mi = 0; mi < 4; mi++)
            #pragma unroll
            for (int r = 0; r < 4; r++) {
                size_t base = (size_t)(row0 + mi * 16 + r) * N + col0;
                #pragma unroll
                for (int ni = 0; ni < 4; ni++)
                    C[base + ni * 16] = acc[mi][ni][r];
            }
    }
}

extern "C" void kernel_launch(void* const* d_in, const int* in_sizes, int n_in,
                              void* d_out, int out_size, void* d_ws, size_t ws_size,
                              hipStream_t stream) {
    const float* x0 = (const float*)d_in[0];
    const float* x1 = (const float*)d_in[1];
    const float* W0 = (const float*)d_in[2];
    const float* W1 = (const float*)d_in[3];
    const float* W2 = (const float*)d_in[4];

    char* ws = (char*)d_ws;
    const size_t MB = 1024 * 1024;
    bf16* Wt0 = (bf16*)(ws + 0 * MB);
    bf16* Wt1 = (bf16*)(ws + 8 * MB);
    bf16* Wt2 = (bf16*)(ws + 16 * MB);

    bf16 *Apk, *z1, *z2;
    if (ws_size >= 56 * MB) {
        // all scratch in ws
        Apk = (bf16*)(ws + 24 * MB);
        z1  = (bf16*)(ws + 40 * MB);
        z2  = Apk;                               // Apk dead after GEMM1
    } else {
        // pack Apk and z1 into the two halves of d_out (32 MB fp32 = 2 x 16 MB bf16);
        // final GEMM reads z2 from ws and fully overwrites d_out.
        Apk = (bf16*)d_out;
        z1  = (bf16*)d_out + (size_t)M * K;      // second 16 MB half
        z2  = (bf16*)(ws + 24 * MB);
    }

    pack_x_kernel<<<(M * K / 8) / 256, 256, 0, stream>>>(x0, x1, Apk);
    transpose_w_kernel<<<dim3(N / 32, K / 32), dim3(32, 8), 0, stream>>>(W0, Wt0);
    transpose_w_kernel<<<dim3(N / 32, K / 32), dim3(32, 8), 0, stream>>>(W1, Wt1);
    transpose_w_kernel<<<dim3(N / 32, K / 32), dim3(32, 8), 0, stream>>>(W2, Wt2);

    constexpr int grid = (M / 128) * (N / 128);  // 512
    gemm_kernel<true ><<<grid, 256, 0, stream>>>(Apk, Wt0, z1);
    gemm_kernel<true ><<<grid, 256, 0, stream>>>(z1,  Wt1, z2);
    gemm_kernel<false><<<grid, 256, 0, stream>>>(z2,  Wt2, (float*)d_out);
}

// Round 2
// 140.607 us; speedup vs baseline: 1.1576x; 1.1576x over previous
//
#include <hip/hip_runtime.h>
#include <hip/hip_bf16.h>
#include <stdint.h>

typedef __bf16 bf16;
typedef __bf16 bf16x8 __attribute__((ext_vector_type(8)));
typedef float f32x4 __attribute__((ext_vector_type(4)));

#define GAS __attribute__((address_space(1)))
#define LAS __attribute__((address_space(3)))

static constexpr int M = 4096;   // batch
static constexpr int N = 2048;   // 2C
static constexpr int K = 2048;   // 2C

static constexpr int BM = 128, BN = 256, BK = 64;
static constexpr int NT = K / BK;               // 32 K-tiles
static constexpr int A_ELE = BM * BK;           // 8192 bf16 = 16 KB
static constexpr int B_ELE = BN * BK;           // 16384 bf16 = 32 KB
static constexpr int BUF_ELE = A_ELE + B_ELE;   // 24576 bf16 = 48 KB; x3 = 144 KB LDS

// --- async global->LDS, 16B per lane, dest = wave-uniform base + lane*16 ---
__device__ __forceinline__ void gload_lds16(const bf16* gsrc, bf16* ldst) {
    __builtin_amdgcn_global_load_lds((const GAS void*)gsrc, (LAS void*)ldst, 16, 0, 0);
}

// --- pack concat(x0,x1) [M][K] fp32 -> bf16, vectorized 8 elems/thread ---
__global__ __launch_bounds__(256) void pack_x_kernel(const float* __restrict__ x0,
                                                     const float* __restrict__ x1,
                                                     bf16* __restrict__ A) {
    int idx = (blockIdx.x * 256 + threadIdx.x) * 8;   // 8-chunks never straddle the 1024 seam
    int b = idx >> 11;
    int c = idx & 2047;
    const float* src = (c < 1024) ? (x0 + (size_t)b * 1024 + c)
                                  : (x1 + (size_t)b * 1024 + (c - 1024));
    float4 v0 = *reinterpret_cast<const float4*>(src);
    float4 v1 = *reinterpret_cast<const float4*>(src + 4);
    bf16x8 o;
    o[0] = (bf16)v0.x; o[1] = (bf16)v0.y; o[2] = (bf16)v0.z; o[3] = (bf16)v0.w;
    o[4] = (bf16)v1.x; o[5] = (bf16)v1.y; o[6] = (bf16)v1.z; o[7] = (bf16)v1.w;
    *reinterpret_cast<bf16x8*>(A + idx) = o;
}

// --- W [K][N] fp32 -> Wt [N][K] bf16 (LDS-tiled transpose, coalesced both sides) ---
__global__ __launch_bounds__(256) void transpose_w_kernel(const float* __restrict__ W,
                                                          bf16* __restrict__ Wt) {
    __shared__ bf16 tile[32][33];
    int n0 = blockIdx.x * 32;
    int k0 = blockIdx.y * 32;
    int tx = threadIdx.x;   // 0..31
    int ty = threadIdx.y;   // 0..7
    #pragma unroll
    for (int i = 0; i < 4; i++) {
        int k = ty + i * 8;
        tile[k][tx] = (bf16)W[(size_t)(k0 + k) * N + n0 + tx];
    }
    __syncthreads();
    #pragma unroll
    for (int i = 0; i < 4; i++) {
        int n = ty + i * 8;
        Wt[(size_t)(n0 + n) * K + k0 + tx] = tile[tx][n];   // Wt[n][k] = W[k][n]
    }
}

// --- 128x256-tile bf16 GEMM: BK=64, 8 waves (2Mx4N, 64x64/wave), 3 LDS buffers,
//     depth-2 prefetch with counted vmcnt (T3+T4), XOR slot-swizzle (T2), setprio (T5).
//     grid = (M/128)*(N/256) = 256 blocks exactly = 1 block/CU. ---
template <bool OUT_BF16>
__global__ __launch_bounds__(512, 2) void gemm8_kernel(const bf16* __restrict__ A,   // [M][K]
                                                       const bf16* __restrict__ Bt,  // [N][K]
                                                       void* __restrict__ Cout) {    // [M][N]
    __shared__ bf16 lds[3 * BUF_ELE];   // 144 KB

    // XCD-aware bijective swizzle (256 blocks, 256 % 8 == 0)
    int bid = blockIdx.x;
    int cpx = gridDim.x >> 3;                    // 32
    int swz = (bid & 7) * cpx + (bid >> 3);
    int tm = swz >> 3;                           // 0..31  (ntn = N/BN = 8)
    int tn = swz & 7;

    int tid  = threadIdx.x;
    int wave = tid >> 6;        // 0..7
    int lane = tid & 63;
    int wr = wave >> 2;         // 0..1  (M quadrant)
    int wc = wave & 3;          // 0..3  (N quadrant)
    int fr = lane & 15;
    int fb = lane >> 4;

    // ---- staging geometry: 6 x gload_lds16 per thread per K-tile ----
    // chunk = 64 rows x 64 cols; thread covers row (wave*8 + lane>>3), 16B slot (lane&7).
    // T2 swizzle: LDS stays LINEAR (gload_lds constraint); global SOURCE column is
    // pre-swizzled so LDS slot s of row r holds global slot s^(r&7). r&7 == lane>>3.
    int srow = wave * 8 + (lane >> 3);
    int scol = ((lane & 7) ^ (lane >> 3)) * 8;            // bf16 col within BK
    const bf16* aS = A  + (size_t)(tm * BM + srow) * K + scol;
    const bf16* bS = Bt + (size_t)(tn * BN + srow) * K + scol;
    int sdst = wave * 512;                                 // elems; HW adds lane*8 elems

    f32x4 acc[4][4] = {};

    auto STAGE = [&](int bi, int t) {
        bf16* ba = (bf16*)lds + bi * BUF_ELE;
        bf16* bb = ba + A_ELE;
        const bf16* a = aS + t * BK;
        const bf16* b = bS + t * BK;
        gload_lds16(a,           ba + sdst);
        gload_lds16(a + 64 * K,  ba + sdst + 4096);
        gload_lds16(b,           bb + sdst);
        gload_lds16(b + 64 * K,  bb + sdst + 4096);
        gload_lds16(b + 128 * K, bb + sdst + 8192);
        gload_lds16(b + 192 * K, bb + sdst + 12288);
    };

    // frag reads: same (lane,elem)->k bijection for A and B (k-permutation invariant);
    // read addr applies the same XOR: slot = (ks*4+fb) ^ (fr&7)  -> 2 lanes/bank (free).
    auto COMPUTE = [&](int bi) {
        const bf16* ba = (const bf16*)lds + bi * BUF_ELE;
        const bf16* bb = ba + A_ELE;
        bf16x8 af[4][2], bfr[4][2];
        #pragma unroll
        for (int mi = 0; mi < 4; mi++)
            #pragma unroll
            for (int ks = 0; ks < 2; ks++)
                af[mi][ks] = *reinterpret_cast<const bf16x8*>(
                    ba + (wr * 64 + mi * 16 + fr) * 64 + ((((ks << 2) | fb) ^ (fr & 7)) * 8));
        #pragma unroll
        for (int ni = 0; ni < 4; ni++)
            #pragma unroll
            for (int ks = 0; ks < 2; ks++)
                bfr[ni][ks] = *reinterpret_cast<const bf16x8*>(
                    bb + (wc * 64 + ni * 16 + fr) * 64 + ((((ks << 2) | fb) ^ (fr & 7)) * 8));
        __builtin_amdgcn_s_setprio(1);
        #pragma unroll
        for (int ks = 0; ks < 2; ks++)
            #pragma unroll
            for (int mi = 0; mi < 4; mi++)
                #pragma unroll
                for (int ni = 0; ni < 4; ni++)
                    acc[mi][ni] = __builtin_amdgcn_mfma_f32_16x16x32_bf16(
                        af[mi][ks], bfr[ni][ks], acc[mi][ni], 0, 0, 0);
        __builtin_amdgcn_s_setprio(0);
    };

    // ---- pipeline: tile t computes from buf[t%3]; t+1 fully staged; t+2 in flight ----
    STAGE(0, 0);
    STAGE(1, 1);
    int cur = 0;
    for (int t = 0; t < NT - 2; t++) {
        int nb = cur + 2; if (nb >= 3) nb -= 3;
        STAGE(nb, t + 2);                                  // 18 outstanding max
        asm volatile("s_waitcnt vmcnt(12)" ::: "memory");  // tile t's 6 loads drained
        __builtin_amdgcn_s_barrier();                      // all waves' tile-t loads visible
        COMPUTE(cur);
        asm volatile("s_waitcnt lgkmcnt(0)" ::: "memory"); // my reads of buf[cur] done
        __builtin_amdgcn_s_barrier();                      // before anyone overwrites it
        cur = cur + 1; if (cur >= 3) cur -= 3;
    }
    asm volatile("s_waitcnt vmcnt(6)" ::: "memory");       // tile NT-2 staged
    __builtin_amdgcn_s_barrier();
    COMPUTE(cur);
    cur = cur + 1; if (cur >= 3) cur -= 3;
    asm volatile("s_waitcnt vmcnt(0)" ::: "memory");       // tile NT-1 staged
    __builtin_amdgcn_s_barrier();
    COMPUTE(cur);

    // ---- epilogue: C/D layout col = lane&15, row = (lane>>4)*4 + reg ----
    int row0 = tm * BM + wr * 64 + (lane >> 4) * 4;
    int col0 = tn * BN + wc * 64 + (lane & 15);
    if constexpr (OUT_BF16) {
        bf16* C = (bf16*)Cout;
        #pragma unroll
        for (int mi = 0; mi < 4; mi++)
            #pragma unroll
            for (int r = 0; r < 4; r++) {
                size_t base = (size_t)(row0 + mi * 16 + r) * N + col0;
                #pragma unroll
                for (int ni = 0; ni < 4; ni++)
                    C[base + ni * 16] = (bf16)acc[mi][ni][r];
            }
    } else {
        float* C = (float*)Cout;
        #pragma unroll
        for (int mi = 0; mi < 4; mi++)
            #pragma unroll
            for (int r = 0; r < 4; r++) {
                size_t base = (size_t)(row0 + mi * 16 + r) * N + col0;
                #pragma unroll
                for (int ni = 0; ni < 4; ni++)
                    C[base + ni * 16] = acc[mi][ni][r];
            }
    }
}

extern "C" void kernel_launch(void* const* d_in, const int* in_sizes, int n_in,
                              void* d_out, int out_size, void* d_ws, size_t ws_size,
                              hipStream_t stream) {
    const float* x0 = (const float*)d_in[0];
    const float* x1 = (const float*)d_in[1];
    const float* W0 = (const float*)d_in[2];
    const float* W1 = (const float*)d_in[3];
    const float* W2 = (const float*)d_in[4];

    char* ws = (char*)d_ws;
    const size_t MB = 1024 * 1024;
    bf16* Wt0 = (bf16*)(ws + 0 * MB);
    bf16* Wt1 = (bf16*)(ws + 8 * MB);
    bf16* Wt2 = (bf16*)(ws + 16 * MB);

    bf16 *Apk, *z1, *z2;
    if (ws_size >= 56 * MB) {
        Apk = (bf16*)(ws + 24 * MB);
        z1  = (bf16*)(ws + 40 * MB);
        z2  = Apk;                               // Apk dead after GEMM1
    } else {
        Apk = (bf16*)d_out;
        z1  = (bf16*)d_out + (size_t)M * K;      // second 16 MB half of d_out
        z2  = (bf16*)(ws + 24 * MB);
    }

    pack_x_kernel<<<(M * K / 8) / 256, 256, 0, stream>>>(x0, x1, Apk);
    transpose_w_kernel<<<dim3(N / 32, K / 32), dim3(32, 8), 0, stream>>>(W0, Wt0);
    transpose_w_kernel<<<dim3(N / 32, K / 32), dim3(32, 8), 0, stream>>>(W1, Wt1);
    transpose_w_kernel<<<dim3(N / 32, K / 32), dim3(32, 8), 0, stream>>>(W2, Wt2);

    constexpr int grid = (M / BM) * (N / BN);    // 32 * 8 = 256
    gemm8_kernel<true ><<<grid, 512, 0, stream>>>(Apk, Wt0, z1);
    gemm8_kernel<true ><<<grid, 512, 0, stream>>>(z1,  Wt1, z2);
    gemm8_kernel<false><<<grid, 512, 0, stream>>>(z2,  Wt2, (float*)d_out);
}

// Round 4
// 128.886 us; speedup vs baseline: 1.2628x; 1.0909x over previous
//
#include <hip/hip_runtime.h>
#include <hip/hip_bf16.h>
#include <stdint.h>

typedef __bf16 bf16;
typedef __bf16 bf16x8 __attribute__((ext_vector_type(8)));
typedef float f32x4 __attribute__((ext_vector_type(4)));

#define GAS __attribute__((address_space(1)))
#define LAS __attribute__((address_space(3)))

static constexpr int M = 4096;   // batch
static constexpr int N = 2048;   // 2C
static constexpr int K = 2048;   // 2C

static constexpr int BM = 128, BN = 256, BK = 64;
static constexpr int NT = K / BK;               // 32 K-tiles
static constexpr int A_ELE = BM * BK;           // 8192 bf16 = 16 KB
static constexpr int B_ELE = BN * BK;           // 16384 bf16 = 32 KB
static constexpr int BUF_ELE = A_ELE + B_ELE;   // 48 KB; x3 = 144 KB LDS

// --- async global->LDS, 16B per lane, dest = wave-uniform base + lane*16 ---
__device__ __forceinline__ void gload_lds16(const bf16* gsrc, bf16* ldst) {
    __builtin_amdgcn_global_load_lds((const GAS void*)gsrc, (LAS void*)ldst, 16, 0, 0);
}

// --- merged prep: pack concat(x0,x1)->bf16  +  3x W[K][N]fp32 -> Wt[N][K]bf16 ---
// pack partition: M*K/8/256 = 4096 blocks (R3 bug: was 2048 -> half of A unpacked)
__global__ __launch_bounds__(256) void prep_kernel(const float* __restrict__ x0,
                                                   const float* __restrict__ x1,
                                                   const float* __restrict__ W0,
                                                   const float* __restrict__ W1,
                                                   const float* __restrict__ W2,
                                                   bf16* __restrict__ A,
                                                   bf16* __restrict__ Wt0,
                                                   bf16* __restrict__ Wt1,
                                                   bf16* __restrict__ Wt2) {
    __shared__ bf16 tile[32][33];
    int bid = blockIdx.x;
    int tid = threadIdx.x;
    if (bid < 4096) {
        // pack: 8 elems/thread; 8-chunks never straddle the 1024 seam
        int idx = (bid * 256 + tid) * 8;
        int b = idx >> 11;
        int c = idx & 2047;
        const float* src = (c < 1024) ? (x0 + (size_t)b * 1024 + c)
                                      : (x1 + (size_t)b * 1024 + (c - 1024));
        float4 v0 = *reinterpret_cast<const float4*>(src);
        float4 v1 = *reinterpret_cast<const float4*>(src + 4);
        bf16x8 o;
        o[0] = (bf16)v0.x; o[1] = (bf16)v0.y; o[2] = (bf16)v0.z; o[3] = (bf16)v0.w;
        o[4] = (bf16)v1.x; o[5] = (bf16)v1.y; o[6] = (bf16)v1.z; o[7] = (bf16)v1.w;
        *reinterpret_cast<bf16x8*>(A + idx) = o;
    } else {
        int r = bid - 4096;
        int w = r >> 12;                 // which W (4096 tiles each)
        int t = r & 4095;
        const float* W  = (w == 0) ? W0  : (w == 1) ? W1  : W2;
        bf16*        Wt = (w == 0) ? Wt0 : (w == 1) ? Wt1 : Wt2;
        int n0 = (t & 63) * 32;
        int k0 = (t >> 6) * 32;
        int tx = tid & 31;
        int ty = tid >> 5;
        #pragma unroll
        for (int i = 0; i < 4; i++) {
            int k = ty + i * 8;
            tile[k][tx] = (bf16)W[(size_t)(k0 + k) * N + n0 + tx];
        }
        __syncthreads();
        #pragma unroll
        for (int i = 0; i < 4; i++) {
            int n = ty + i * 8;
            Wt[(size_t)(n0 + n) * K + k0 + tx] = tile[tx][n];   // Wt[n][k] = W[k][n]
        }
    }
}

// --- fragment reads for one k-half (ks): same (lane,elem)->k bijection for A and B ---
__device__ __forceinline__ void read_frags(const bf16* __restrict__ ba, const bf16* __restrict__ bb,
                                           int aoff, int boff, int slot,
                                           bf16x8 af[4], bf16x8 bv[4]) {
    #pragma unroll
    for (int mi = 0; mi < 4; mi++)
        af[mi] = *reinterpret_cast<const bf16x8*>(ba + aoff + mi * 1024 + slot);
    #pragma unroll
    for (int ni = 0; ni < 4; ni++)
        bv[ni] = *reinterpret_cast<const bf16x8*>(bb + boff + ni * 1024 + slot);
}

__device__ __forceinline__ void do_mfma16(const bf16x8 af[4], const bf16x8 bv[4], f32x4 acc[4][4]) {
    __builtin_amdgcn_s_setprio(1);
    #pragma unroll
    for (int mi = 0; mi < 4; mi++)
        #pragma unroll
        for (int ni = 0; ni < 4; ni++)
            acc[mi][ni] = __builtin_amdgcn_mfma_f32_16x16x32_bf16(af[mi], bv[ni], acc[mi][ni], 0, 0, 0);
    __builtin_amdgcn_s_setprio(0);
}

// --- 128x256-tile bf16 GEMM, phase-split pipeline (T2+T3+T4+T5):
//     BK=64, 8 waves (2Mx4N, 64x64/wave), 3 rotating LDS buffers (depth-2 HBM prefetch),
//     per K-tile: 2 phases {8 ds_read ∥ 3 gload_lds -> bar -> lgkm(0) -> 16 MFMA -> bar},
//     vmcnt(6) once per K-tile (never 0 in main loop). grid=256 = 1 block/CU. ---
template <bool OUT_BF16>
__global__ __launch_bounds__(512, 2) void gemm8p_kernel(const bf16* __restrict__ A,   // [M][K]
                                                        const bf16* __restrict__ Bt,  // [N][K]
                                                        void* __restrict__ Cout) {    // [M][N]
    __shared__ bf16 lds[3 * BUF_ELE];   // 144 KB

    // XCD-aware bijective swizzle (256 blocks, 256 % 8 == 0)
    int bid = blockIdx.x;
    int cpx = gridDim.x >> 3;
    int swz = (bid & 7) * cpx + (bid >> 3);
    int tm = swz >> 3;                           // 0..31
    int tn = swz & 7;                            // 0..7

    int tid  = threadIdx.x;
    int wave = tid >> 6;        // 0..7
    int lane = tid & 63;
    int wr = wave >> 2;         // 0..1  (M half)
    int wc = wave & 3;          // 0..3  (N quarter)
    int fr = lane & 15;
    int fb = lane >> 4;

    // staging geometry: thread covers row (wave*8 + lane>>3), pre-swizzled global 16B slot
    int srow = wave * 8 + (lane >> 3);
    int scol = ((lane & 7) ^ (lane >> 3)) * 8;            // T2: source col pre-swizzle (rule #21)
    const bf16* aS = A  + (size_t)(tm * BM + srow) * K + scol;
    const bf16* bS = Bt + (size_t)(tn * BN + srow) * K + scol;
    int sdst = wave * 512;                                 // elems; HW adds lane*16B

    // read geometry: LDS slot = gslot ^ (row&7), row&7 == fr&7
    int aoff  = (wr * 64 + fr) * 64;
    int boff  = (wc * 64 + fr) * 64;
    int slot0 = ((fb) ^ (fr & 7)) * 8;                     // ks=0: gslot = fb
    int slot1 = ((4 | fb) ^ (fr & 7)) * 8;                 // ks=1: gslot = 4+fb

    f32x4 acc[4][4] = {};

    auto STAGE_A = [&](int bi, int t) {                    // 2 loads (A rows 0-63, 64-127)
        bf16* ba = (bf16*)lds + bi * BUF_ELE;
        const bf16* a = aS + t * BK;
        gload_lds16(a,          ba + sdst);
        gload_lds16(a + 64 * K, ba + sdst + 4096);
    };
    auto STAGE_B0 = [&](int bi, int t) {                   // 1 load (B rows 0-63)
        bf16* bb = (bf16*)lds + bi * BUF_ELE + A_ELE;
        gload_lds16(bS + t * BK, bb + sdst);
    };
    auto STAGE_B123 = [&](int bi, int t) {                 // 3 loads (B rows 64-255)
        bf16* bb = (bf16*)lds + bi * BUF_ELE + A_ELE;
        const bf16* b = bS + t * BK;
        gload_lds16(b + 64 * K,  bb + sdst + 4096);
        gload_lds16(b + 128 * K, bb + sdst + 8192);
        gload_lds16(b + 192 * K, bb + sdst + 12288);
    };

    // ---- prologue: tiles 0,1 staged; wait tile 0 resident ----
    STAGE_A(0, 0); STAGE_B0(0, 0); STAGE_B123(0, 0);
    STAGE_A(1, 1); STAGE_B0(1, 1); STAGE_B123(1, 1);
    asm volatile("s_waitcnt vmcnt(6)" ::: "memory");
    __builtin_amdgcn_s_barrier();

    bf16x8 af[4], bv[4];
    int cur = 0;
    // ---- main loop: compute tile t from buf[cur], stage tile t+2 ----
    for (int t = 0; t < NT - 2; ++t) {
        const bf16* ba = (const bf16*)lds + cur * BUF_ELE;
        const bf16* bb = ba + A_ELE;
        int sb = cur + 2; if (sb >= 3) sb -= 3;

        // phase 0 (ks=0)
        read_frags(ba, bb, aoff, boff, slot0, af, bv);
        STAGE_A(sb, t + 2); STAGE_B0(sb, t + 2);
        __builtin_amdgcn_s_barrier();
        asm volatile("s_waitcnt lgkmcnt(0)" ::: "memory");
        do_mfma16(af, bv, acc);
        __builtin_amdgcn_s_barrier();

        // phase 1 (ks=1)
        read_frags(ba, bb, aoff, boff, slot1, af, bv);
        STAGE_B123(sb, t + 2);
        __builtin_amdgcn_s_barrier();
        asm volatile("s_waitcnt lgkmcnt(0)" ::: "memory");
        do_mfma16(af, bv, acc);
        asm volatile("s_waitcnt vmcnt(6)" ::: "memory");   // tile t+1 resident; t+2 in flight
        __builtin_amdgcn_s_barrier();

        cur = cur + 1; if (cur >= 3) cur -= 3;
    }
    // ---- t = NT-2: no staging; drain tile NT-1 at end ----
    {
        const bf16* ba = (const bf16*)lds + cur * BUF_ELE;
        const bf16* bb = ba + A_ELE;
        read_frags(ba, bb, aoff, boff, slot0, af, bv);
        __builtin_amdgcn_s_barrier();
        asm volatile("s_waitcnt lgkmcnt(0)" ::: "memory");
        do_mfma16(af, bv, acc);
        __builtin_amdgcn_s_barrier();
        read_frags(ba, bb, aoff, boff, slot1, af, bv);
        __builtin_amdgcn_s_barrier();
        asm volatile("s_waitcnt lgkmcnt(0)" ::: "memory");
        do_mfma16(af, bv, acc);
        asm volatile("s_waitcnt vmcnt(0)" ::: "memory");
        __builtin_amdgcn_s_barrier();
        cur = cur + 1; if (cur >= 3) cur -= 3;
    }
    // ---- t = NT-1: compute only ----
    {
        const bf16* ba = (const bf16*)lds + cur * BUF_ELE;
        const bf16* bb = ba + A_ELE;
        read_frags(ba, bb, aoff, boff, slot0, af, bv);
        asm volatile("s_waitcnt lgkmcnt(0)" ::: "memory");
        do_mfma16(af, bv, acc);
        read_frags(ba, bb, aoff, boff, slot1, af, bv);
        asm volatile("s_waitcnt lgkmcnt(0)" ::: "memory");
        do_mfma16(af, bv, acc);
    }

    // ---- epilogue: C/D layout col = lane&15, row = (lane>>4)*4 + reg ----
    int row0 = tm * BM + wr * 64 + (lane >> 4) * 4;
    int col0 = tn * BN + wc * 64 + (lane & 15);
    if constexpr (OUT_BF16) {
        bf16* C = (bf16*)Cout;
        #pragma unroll
        for (int mi = 0; mi < 4; mi++)
            #pragma unroll
            for (int r = 0; r < 4; r++) {
                size_t base = (size_t)(row0 + mi * 16 + r) * N + col0;
                #pragma unroll
                for (int ni = 0; ni < 4; ni++)
                    C[base + ni * 16] = (bf16)acc[mi][ni][r];
            }
    } else {
        float* C = (float*)Cout;
        #pragma unroll
        for (int mi = 0; mi < 4; mi++)
            #pragma unroll
            for (int r = 0; r < 4; r++) {
                size_t base = (size_t)(row0 + mi * 16 + r) * N + col0;
                #pragma unroll
                for (int ni = 0; ni < 4; ni++)
                    C[base + ni * 16] = acc[mi][ni][r];
            }
    }
}

extern "C" void kernel_launch(void* const* d_in, const int* in_sizes, int n_in,
                              void* d_out, int out_size, void* d_ws, size_t ws_size,
                              hipStream_t stream) {
    const float* x0 = (const float*)d_in[0];
    const float* x1 = (const float*)d_in[1];
    const float* W0 = (const float*)d_in[2];
    const float* W1 = (const float*)d_in[3];
    const float* W2 = (const float*)d_in[4];

    char* ws = (char*)d_ws;
    const size_t MB = 1024 * 1024;
    bf16* Wt0 = (bf16*)(ws + 0 * MB);
    bf16* Wt1 = (bf16*)(ws + 8 * MB);
    bf16* Wt2 = (bf16*)(ws + 16 * MB);

    bf16 *Apk, *z1, *z2;
    if (ws_size >= 56 * MB) {
        Apk = (bf16*)(ws + 24 * MB);
        z1  = (bf16*)(ws + 40 * MB);
        z2  = Apk;                               // Apk dead after GEMM1
    } else {
        Apk = (bf16*)d_out;
        z1  = (bf16*)d_out + (size_t)M * K;      // second half of d_out
        z2  = (bf16*)(ws + 24 * MB);
    }

    prep_kernel<<<4096 + 3 * 4096, 256, 0, stream>>>(x0, x1, W0, W1, W2, Apk, Wt0, Wt1, Wt2);

    constexpr int grid = (M / BM) * (N / BN);    // 32 * 8 = 256
    gemm8p_kernel<true ><<<grid, 512, 0, stream>>>(Apk, Wt0, z1);
    gemm8p_kernel<true ><<<grid, 512, 0, stream>>>(z1,  Wt1, z2);
    gemm8p_kernel<false><<<grid, 512, 0, stream>>>(z2,  Wt2, (float*)d_out);
}

// Round 5
// 123.475 us; speedup vs baseline: 1.3182x; 1.0438x over previous
//
#include <hip/hip_runtime.h>
#include <hip/hip_bf16.h>
#include <stdint.h>

typedef __bf16 bf16;
typedef __bf16 bf16x8 __attribute__((ext_vector_type(8)));
typedef float f32x4 __attribute__((ext_vector_type(4)));

#define GAS __attribute__((address_space(1)))
#define LAS __attribute__((address_space(3)))

static constexpr int M = 4096;   // batch
static constexpr int N = 2048;   // 2C
static constexpr int K = 2048;   // 2C

static constexpr int BM = 128, BN = 256, BK = 64;
static constexpr int NT = K / BK;               // 32 K-tiles
static constexpr int A_ELE = BM * BK;           // 8192 bf16 = 16 KB
static constexpr int B_ELE = BN * BK;           // 16384 bf16 = 32 KB
static constexpr int BUF_ELE = A_ELE + B_ELE;   // 48 KB; x3 = 144 KB LDS

// --- async global->LDS, 16B per lane, dest = wave-uniform base + lane*16 ---
__device__ __forceinline__ void gload_lds16(const bf16* gsrc, bf16* ldst) {
    __builtin_amdgcn_global_load_lds((const GAS void*)gsrc, (LAS void*)ldst, 16, 0, 0);
}

// --- merged prep: pack concat(x0,x1)->bf16  +  3x W[K][N]fp32 -> Wt[N][K]bf16 ---
__global__ __launch_bounds__(256) void prep_kernel(const float* __restrict__ x0,
                                                   const float* __restrict__ x1,
                                                   const float* __restrict__ W0,
                                                   const float* __restrict__ W1,
                                                   const float* __restrict__ W2,
                                                   bf16* __restrict__ A,
                                                   bf16* __restrict__ Wt0,
                                                   bf16* __restrict__ Wt1,
                                                   bf16* __restrict__ Wt2) {
    __shared__ bf16 tile[32][33];
    int bid = blockIdx.x;
    int tid = threadIdx.x;
    if (bid < 4096) {
        // pack: 8 elems/thread; 8-chunks never straddle the 1024 seam
        int idx = (bid * 256 + tid) * 8;
        int b = idx >> 11;
        int c = idx & 2047;
        const float* src = (c < 1024) ? (x0 + (size_t)b * 1024 + c)
                                      : (x1 + (size_t)b * 1024 + (c - 1024));
        float4 v0 = *reinterpret_cast<const float4*>(src);
        float4 v1 = *reinterpret_cast<const float4*>(src + 4);
        bf16x8 o;
        o[0] = (bf16)v0.x; o[1] = (bf16)v0.y; o[2] = (bf16)v0.z; o[3] = (bf16)v0.w;
        o[4] = (bf16)v1.x; o[5] = (bf16)v1.y; o[6] = (bf16)v1.z; o[7] = (bf16)v1.w;
        *reinterpret_cast<bf16x8*>(A + idx) = o;
    } else {
        int r = bid - 4096;
        int w = r >> 12;                 // which W (4096 tiles each)
        int t = r & 4095;
        const float* W  = (w == 0) ? W0  : (w == 1) ? W1  : W2;
        bf16*        Wt = (w == 0) ? Wt0 : (w == 1) ? Wt1 : Wt2;
        int n0 = (t & 63) * 32;
        int k0 = (t >> 6) * 32;
        int tx = tid & 31;
        int ty = tid >> 5;
        #pragma unroll
        for (int i = 0; i < 4; i++) {
            int k = ty + i * 8;
            tile[k][tx] = (bf16)W[(size_t)(k0 + k) * N + n0 + tx];
        }
        __syncthreads();
        #pragma unroll
        for (int i = 0; i < 4; i++) {
            int n = ty + i * 8;
            Wt[(size_t)(n0 + n) * K + k0 + tx] = tile[tx][n];   // Wt[n][k] = W[k][n]
        }
    }
}

__device__ __forceinline__ void read_frags(const bf16* __restrict__ ba, const bf16* __restrict__ bb,
                                           int aoff, int boff, int slot,
                                           bf16x8 af[4], bf16x8 bv[4]) {
    #pragma unroll
    for (int mi = 0; mi < 4; mi++)
        af[mi] = *reinterpret_cast<const bf16x8*>(ba + aoff + mi * 1024 + slot);
    #pragma unroll
    for (int ni = 0; ni < 4; ni++)
        bv[ni] = *reinterpret_cast<const bf16x8*>(bb + boff + ni * 1024 + slot);
}

__device__ __forceinline__ void do_mfma16(const bf16x8 af[4], const bf16x8 bv[4], f32x4 acc[4][4]) {
    __builtin_amdgcn_s_setprio(1);
    #pragma unroll
    for (int mi = 0; mi < 4; mi++)
        #pragma unroll
        for (int ni = 0; ni < 4; ni++)
            acc[mi][ni] = __builtin_amdgcn_mfma_f32_16x16x32_bf16(af[mi], bv[ni], acc[mi][ni], 0, 0, 0);
    __builtin_amdgcn_s_setprio(0);
}

// --- 128x256-tile bf16 GEMM: BK=64, 8 waves (2Mx4N), 3 rotating LDS buffers,
//     ONE barrier per K-tile; lgkmcnt-split register pipeline:
//     issue 16 ds_read + 6 gload -> lgkm(8) -> MFMA ks0 (ks1 reads land under it)
//     -> lgkm(0) -> MFMA ks1 -> vmcnt(6) -> barrier.  LDS floor 1536 cyc/tile. ---
template <bool OUT_BF16>
__global__ __launch_bounds__(512, 2) void gemm1b_kernel(const bf16* __restrict__ A,   // [M][K]
                                                        const bf16* __restrict__ Bt,  // [N][K]
                                                        void* __restrict__ Cout) {    // [M][N]
    __shared__ bf16 lds[3 * BUF_ELE];   // 144 KB

    // XCD-aware bijective swizzle (256 blocks, 256 % 8 == 0)
    int bid = blockIdx.x;
    int cpx = gridDim.x >> 3;
    int swz = (bid & 7) * cpx + (bid >> 3);
    int tm = swz >> 3;                           // 0..31
    int tn = swz & 7;                            // 0..7

    int tid  = threadIdx.x;
    int wave = tid >> 6;        // 0..7
    int lane = tid & 63;
    int wr = wave >> 2;         // 0..1  (M half)
    int wc = wave & 3;          // 0..3  (N quarter)
    int fr = lane & 15;
    int fb = lane >> 4;

    // staging geometry: thread covers row (wave*8 + lane>>3), pre-swizzled global 16B slot
    int srow = wave * 8 + (lane >> 3);
    int scol = ((lane & 7) ^ (lane >> 3)) * 8;            // T2: source col pre-swizzle (rule #21)
    const bf16* aS = A  + (size_t)(tm * BM + srow) * K + scol;
    const bf16* bS = Bt + (size_t)(tn * BN + srow) * K + scol;
    int sdst = wave * 512;                                 // elems; HW adds lane*16B

    // read geometry: LDS slot = gslot ^ (row&7), row&7 == fr&7
    int aoff  = (wr * 64 + fr) * 64;
    int boff  = (wc * 64 + fr) * 64;
    int slot0 = ((fb) ^ (fr & 7)) * 8;                     // ks=0: gslot = fb
    int slot1 = ((4 | fb) ^ (fr & 7)) * 8;                 // ks=1: gslot = 4+fb

    f32x4 acc[4][4] = {};

    auto STAGE = [&](int bi, int t) {                       // 6 loads: A 2, B 4
        bf16* ba = (bf16*)lds + bi * BUF_ELE;
        bf16* bb = ba + A_ELE;
        const bf16* a = aS + t * BK;
        const bf16* b = bS + t * BK;
        gload_lds16(a,           ba + sdst);
        gload_lds16(a + 64 * K,  ba + sdst + 4096);
        gload_lds16(b,           bb + sdst);
        gload_lds16(b + 64 * K,  bb + sdst + 4096);
        gload_lds16(b + 128 * K, bb + sdst + 8192);
        gload_lds16(b + 192 * K, bb + sdst + 12288);
    };

    // ---- prologue: tiles 0,1 staged; tile 0 resident after barrier ----
    STAGE(0, 0);
    STAGE(1, 1);
    asm volatile("s_waitcnt vmcnt(6)" ::: "memory");
    __builtin_amdgcn_s_barrier();

    bf16x8 af0[4], bv0[4], af1[4], bv1[4];
    int cur = 0;
    // ---- main loop: one barrier per K-tile ----
    for (int t = 0; t < NT - 2; ++t) {
        const bf16* ba = (const bf16*)lds + cur * BUF_ELE;
        const bf16* bb = ba + A_ELE;
        int sb = cur + 2; if (sb >= 3) sb -= 3;

        read_frags(ba, bb, aoff, boff, slot0, af0, bv0);   // 8 ds_read (ks0)
        read_frags(ba, bb, aoff, boff, slot1, af1, bv1);   // 8 ds_read (ks1)
        STAGE(sb, t + 2);                                  // 6 gload (tile t+2); buf read-drained at prev barrier
        asm volatile("s_waitcnt lgkmcnt(8)" ::: "memory"); // ks0 frags resident (DS in-order)
        do_mfma16(af0, bv0, acc);                          // ks1 reads land under these 16 MFMAs
        asm volatile("s_waitcnt lgkmcnt(0)" ::: "memory");
        do_mfma16(af1, bv1, acc);
        asm volatile("s_waitcnt vmcnt(6)" ::: "memory");   // my tile-(t+1) loads landed; t+2 in flight
        __builtin_amdgcn_s_barrier();                      // => tile t+1 resident; buf[t%3] recyclable
        cur = cur + 1; if (cur >= 3) cur -= 3;
    }
    // ---- t = NT-2: no staging; drain tile NT-1 ----
    {
        const bf16* ba = (const bf16*)lds + cur * BUF_ELE;
        const bf16* bb = ba + A_ELE;
        read_frags(ba, bb, aoff, boff, slot0, af0, bv0);
        read_frags(ba, bb, aoff, boff, slot1, af1, bv1);
        asm volatile("s_waitcnt lgkmcnt(8)" ::: "memory");
        do_mfma16(af0, bv0, acc);
        asm volatile("s_waitcnt lgkmcnt(0)" ::: "memory");
        do_mfma16(af1, bv1, acc);
        asm volatile("s_waitcnt vmcnt(0)" ::: "memory");
        __builtin_amdgcn_s_barrier();
        cur = cur + 1; if (cur >= 3) cur -= 3;
    }
    // ---- t = NT-1: compute only ----
    {
        const bf16* ba = (const bf16*)lds + cur * BUF_ELE;
        const bf16* bb = ba + A_ELE;
        read_frags(ba, bb, aoff, boff, slot0, af0, bv0);
        read_frags(ba, bb, aoff, boff, slot1, af1, bv1);
        asm volatile("s_waitcnt lgkmcnt(8)" ::: "memory");
        do_mfma16(af0, bv0, acc);
        asm volatile("s_waitcnt lgkmcnt(0)" ::: "memory");
        do_mfma16(af1, bv1, acc);
    }

    // ---- epilogue: C/D layout col = lane&15, row = (lane>>4)*4 + reg ----
    int row0 = tm * BM + wr * 64 + (lane >> 4) * 4;
    int col0 = tn * BN + wc * 64 + (lane & 15);
    if constexpr (OUT_BF16) {
        bf16* C = (bf16*)Cout;
        #pragma unroll
        for (int mi = 0; mi < 4; mi++)
            #pragma unroll
            for (int r = 0; r < 4; r++) {
                size_t base = (size_t)(row0 + mi * 16 + r) * N + col0;
                #pragma unroll
                for (int ni = 0; ni < 4; ni++)
                    C[base + ni * 16] = (bf16)acc[mi][ni][r];
            }
    } else {
        float* C = (float*)Cout;
        #pragma unroll
        for (int mi = 0; mi < 4; mi++)
            #pragma unroll
            for (int r = 0; r < 4; r++) {
                size_t base = (size_t)(row0 + mi * 16 + r) * N + col0;
                #pragma unroll
                for (int ni = 0; ni < 4; ni++)
                    C[base + ni * 16] = acc[mi][ni][r];
            }
    }
}

extern "C" void kernel_launch(void* const* d_in, const int* in_sizes, int n_in,
                              void* d_out, int out_size, void* d_ws, size_t ws_size,
                              hipStream_t stream) {
    const float* x0 = (const float*)d_in[0];
    const float* x1 = (const float*)d_in[1];
    const float* W0 = (const float*)d_in[2];
    const float* W1 = (const float*)d_in[3];
    const float* W2 = (const float*)d_in[4];

    char* ws = (char*)d_ws;
    const size_t MB = 1024 * 1024;
    bf16* Wt0 = (bf16*)(ws + 0 * MB);
    bf16* Wt1 = (bf16*)(ws + 8 * MB);
    bf16* Wt2 = (bf16*)(ws + 16 * MB);

    bf16 *Apk, *z1, *z2;
    if (ws_size >= 56 * MB) {
        Apk = (bf16*)(ws + 24 * MB);
        z1  = (bf16*)(ws + 40 * MB);
        z2  = Apk;                               // Apk dead after GEMM1
    } else {
        Apk = (bf16*)d_out;
        z1  = (bf16*)d_out + (size_t)M * K;      // second half of d_out
        z2  = (bf16*)(ws + 24 * MB);
    }

    prep_kernel<<<4096 + 3 * 4096, 256, 0, stream>>>(x0, x1, W0, W1, W2, Apk, Wt0, Wt1, Wt2);

    constexpr int grid = (M / BM) * (N / BN);    // 32 * 8 = 256
    gemm1b_kernel<true ><<<grid, 512, 0, stream>>>(Apk, Wt0, z1);
    gemm1b_kernel<true ><<<grid, 512, 0, stream>>>(z1,  Wt1, z2);
    gemm1b_kernel<false><<<grid, 512, 0, stream>>>(z2,  Wt2, (float*)d_out);
}